// Round 7
// baseline (179.015 us; speedup 1.0000x reference)
//
#include <hip/hip_runtime.h>
#include <math.h>

// VectorQuantizer: argmin_k ||x_n - c_k||^2, N=32768, K=8192, D=64, fp32.
// Round-13: BARRIER-FREE main loop -- per-wave private pipelines.
//
// r7-r12 post-mortem: every barriered variant lands at MfmaUtil 30-38%
// (m233's 2-phase ceiling). Measured wall 4875cy/tile/CU vs 1550cy MFMA:
// ~60% idle-issue from barrier convoys (all waves stall at the same
// ds-latency / vmcnt-drain / barrier points; 2 w/SIMD can't cover).
// Fix: NO cross-wave data sharing in the K-loop. Each wave owns a private
// 32-code-group slice; it DMAs its own B+csq data into its own LDS region
// (vmcnt is per-wave -> own s_waitcnt vmcnt(0) is complete sync). The main
// loop has ZERO s_barrier: waves slip freely; when one waits, the other
// wave on the SIMD issues MFMAs.
//  * bSwz layout: per 32-code group, 8448B unit = 8KB planes + 256B csq
//    (32 floats duplicated x2 for the two lane-halves) -> uniform 9-load
//    DMA (8x gload_lds16 + 1x gload_lds4) per wave per body.
//  * Per-wave 2-parity ring (8448B x 2); body t: wait own vmcnt(0) [tile t
//    landed] -> issue tile t+1 DMA -> 9 ds_reads -> epilogue-compare tile
//    t-1 (T15; fills ds-latency window, dies before acc peak) -> 24 MFMA
//    (setprio) -> dist(t) into regs. Safety: buf[(t+1)&1]'s prior reads
//    (body t-1) were consumed by body t-1's MFMAs (compiler lgkm waits),
//    so they completed before body t issues DMA over that region.
//  * LDS 68KB -> 2 blocks/CU; prologue A-split staged transiently in the
//    buffer region, fenced by lgkmcnt(0)+barrier BEFORE tile-0 DMA issue.
// Numerics identical to r12 (passed, absmax 0): 2-plane f16 split (plane1
// denormal-zeroed, plane2 pre-scaled 2^12), 3 products (A=h1g1 4-chain,
// B=h1g2'+h2'g1 8-chain), d = fmaf(-2, fmaf(B,2^-12,A), csq) [xsq omitted:
// per-row const, argmin-invariant], strict < ascending code, fkey-mapped
// u64 mins (negative-d safe) = first-occurrence.
// C/D layout (measured m74/m101): col=lane&31, row=(reg&3)+8*(reg>>2)+4*(lane>>5).

typedef __attribute__((ext_vector_type(8)))  _Float16 h8v;
typedef __attribute__((ext_vector_type(16))) float f16v;

constexpr int NROWS = 32768;
constexpr int KC    = 8192;
constexpr int DD    = 64;
constexpr int TPB   = 256;             // 4 waves, one 32-code group slice each
constexpr int PTPB  = 256;             // pre-kernel block size
constexpr int BROWS = 64;              // rows per block -> 512 blocks = 2/CU
constexpr int GUNIT = 4224;            // halves per group unit: 4096 planes + 128 csq-floats
constexpr int NBODY = 64;              // 256 groups / 4 waves

__device__ __forceinline__ void split2h(float v, _Float16& h1, _Float16& h2) {
  const float av = fabsf(v);
  _Float16 a = (_Float16)v;                  // RNE
  if (av < 6.1035156e-5f) a = (_Float16)0.f; // keep plane-1 out of f16 denormals
  h1 = a;
  h2 = (_Float16)((v - (float)a) * 4096.f);  // exact residual, scaled 2^12
}

__device__ __forceinline__ void gload_lds16(const void* g, void* l) {
  __builtin_amdgcn_global_load_lds(
      (const __attribute__((address_space(1))) void*)g,
      (__attribute__((address_space(3))) void*)l, 16, 0, 0);
}
__device__ __forceinline__ void gload_lds4(const void* g, void* l) {
  __builtin_amdgcn_global_load_lds(
      (const __attribute__((address_space(1))) void*)g,
      (__attribute__((address_space(3))) void*)l, 4, 0, 0);
}

// Monotone map: unsigned order of mapped bits == float order (handles negatives).
__device__ __forceinline__ unsigned fkey(float f) {
  const unsigned u = __float_as_uint(f);
  return u ^ (((unsigned)((int)u >> 31)) | 0x80000000u);
}

// Pre-kernel (128 blocks, 4 threads/code): split cb into frag-ordered group
// units [8KB planes | 256B csq x2-duplicated]. Chunk layout per group:
// chunk (p,kc) = 64 lanes x 8 f16, lane (h*32+l) = code l, k = kc*16+h*8+j.
__global__ void vq_pre_kernel(const float* __restrict__ cb,
                              _Float16* __restrict__ bSwz) {
  const int gidx = blockIdx.x * PTPB + threadIdx.x;  // 0..32767
  const int code = gidx >> 2;
  const int kc4  = gidx & 3;                         // this thread's k-chunk
  const float* cp = cb + (size_t)code * DD + kc4 * 16;
  float v[16];
#pragma unroll
  for (int d = 0; d < 16; d += 4) {
    const float4 g = *(const float4*)(cp + d);
    v[d] = g.x; v[d + 1] = g.y; v[d + 2] = g.z; v[d + 3] = g.w;
  }
  float s = 0.f;
#pragma unroll
  for (int d = 0; d < 16; ++d) s = fmaf(v[d], v[d], s);
  s += __shfl_xor(s, 1, 64);
  s += __shfl_xor(s, 2, 64);
  _Float16 p1[16], p2[16];
#pragma unroll
  for (int d = 0; d < 16; ++d) split2h(v[d], p1[d], p2[d]);
  const int g = code >> 5, l = code & 31;
  _Float16* base = bSwz + (size_t)g * GUNIT;
#pragma unroll
  for (int p = 0; p < 2; ++p) {
    const _Float16* pl = p ? p2 : p1;
#pragma unroll
    for (int h = 0; h < 2; ++h) {
      h8v wv;
#pragma unroll
      for (int j = 0; j < 8; ++j) wv[j] = pl[h * 8 + j];
      *(h8v*)(base + (p * 4 + kc4) * 512 + (h * 32 + l) * 8) = wv;
    }
  }
  if (kc4 == 0) {
    float* cs2 = (float*)(base + 4096);
    cs2[l] = s; cs2[32 + l] = s;     // duplicated for lane-halves
  }
}

__global__ __launch_bounds__(TPB, 2)
void vq_mfma_kernel(const float* __restrict__ x, const _Float16* __restrict__ bSwz,
                    int* __restrict__ out) {
  __shared__ alignas(16) _Float16 ldsBf[2 * 4 * GUNIT];       // 67584 B
  __shared__ alignas(16) unsigned long long ldsRed[BROWS][4]; // 2048 B

  const int tid  = threadIdx.x;
  const int lane = tid & 63;
  const int w    = tid >> 6;     // wave -> group slice (groups w, w+4, ...)
  const int half = lane >> 5;
  const int col  = lane & 31;
  const int blockRow = blockIdx.x * BROWS;

  // ---- Stage A: split 64 x-rows into 2 f16 planes, XOR-swizzled, staged
  // transiently at the start of the buffer region.
  _Float16* ldsA = ldsBf;
  {
    const int row = tid >> 2, dseg = (tid & 3) * 16;
    const float* xp = x + (size_t)(blockRow + row) * DD + dseg;
    float v[16];
#pragma unroll
    for (int d = 0; d < 16; d += 4) {
      const float4 g = *(const float4*)(xp + d);
      v[d] = g.x; v[d + 1] = g.y; v[d + 2] = g.z; v[d + 3] = g.w;
    }
    _Float16 qa[16], qb[16];
#pragma unroll
    for (int e = 0; e < 16; ++e) split2h(v[e], qa[e], qb[e]);
#pragma unroll
    for (int h2 = 0; h2 < 2; ++h2) {
      h8v a, b;
#pragma unroll
      for (int j = 0; j < 8; ++j) { a[j] = qa[h2 * 8 + j]; b[j] = qb[h2 * 8 + j]; }
      const int slot = (tid & 3) * 2 + h2;           // 16B slot (d/8)
      *(h8v*)&ldsA[(0 * 64 + row) * 64 + (slot ^ (row & 7)) * 8] = a;
      *(h8v*)&ldsA[(1 * 64 + row) * 64 + (slot ^ (row & 7)) * 8] = b;
    }
  }
  asm volatile("s_waitcnt lgkmcnt(0)\n\ts_barrier" ::: "memory");

  // ---- A fragments resident: 2 stripes x 2 planes x 4 kchunks = 64 VGPR.
  h8v afr[2][2][4];
#pragma unroll
  for (int q = 0; q < 2; ++q)
#pragma unroll
    for (int p = 0; p < 2; ++p)
#pragma unroll
      for (int kc = 0; kc < 4; ++kc) {
        const int arow = q * 32 + col;
        const int slot = kc * 2 + half;
        afr[q][p][kc] =
            *(const h8v*)&ldsA[(p * 64 + arow) * 64 + ((slot ^ (arow & 7))) * 8];
      }
  // ALL waves' afr reads complete before ANY wave's DMA can land on this region.
  asm volatile("s_waitcnt lgkmcnt(0)\n\ts_barrier" ::: "memory");

  // ---- Issue body-0 DMA (tile 0 = group w) into parity-0 private region.
  {
    const _Float16* gs = bSwz + (size_t)w * GUNIT;
    _Float16* ld = ldsBf + w * GUNIT;
#pragma unroll
    for (int c = 0; c < 8; ++c)
      gload_lds16(gs + c * 512 + lane * 8, ld + c * 512 + lane * 8);
    gload_lds4((const float*)(gs + 4096) + lane, (float*)(ld + 4096));
  }

  float bestD[32];
  unsigned bestC[32];
  float distP[32];
#pragma unroll
  for (int i = 0; i < 32; ++i) {
    bestD[i] = INFINITY; bestC[i] = 0u; distP[i] = INFINITY;  // body-0 epi: no-op
  }
  unsigned codeP = 0u;

  const f16v Z = {0.f,0.f,0.f,0.f,0.f,0.f,0.f,0.f,0.f,0.f,0.f,0.f,0.f,0.f,0.f,0.f};

  for (int t = 0; t < NBODY; ++t) {
    // Own tile-t DMA landed (vmcnt is per-wave; no barrier needed).
    asm volatile("s_waitcnt vmcnt(0)" ::: "memory");
    // Issue tile t+1 into the other parity of this wave's private region.
    if (t + 1 < NBODY) {
      const _Float16* gs = bSwz + (size_t)((t + 1) * 4 + w) * GUNIT;
      _Float16* ld = ldsBf + ((t + 1) & 1) * (4 * GUNIT) + w * GUNIT;
#pragma unroll
      for (int c = 0; c < 8; ++c)
        gload_lds16(gs + c * 512 + lane * 8, ld + c * 512 + lane * 8);
      gload_lds4((const float*)(gs + 4096) + lane, (float*)(ld + 4096));
    }
    // B fragments + csq from the private region (lane-linear, conflict-free).
    const _Float16* rb = ldsBf + (t & 1) * (4 * GUNIT) + w * GUNIT;
    h8v b0[4], b1[4];
#pragma unroll
    for (int kc = 0; kc < 4; ++kc) {
      b0[kc] = *(const h8v*)(rb + kc * 512 + lane * 8);
      b1[kc] = *(const h8v*)(rb + (4 + kc) * 512 + lane * 8);
    }
    const float cs = ((const float*)(rb + 4096))[lane];

    // Epilogue-compare for tile t-1 (prev regs; fills the ds-latency window,
    // distP dies before the accumulator peak).
#pragma unroll
    for (int i = 0; i < 32; ++i)
      if (distP[i] < bestD[i]) { bestD[i] = distP[i]; bestC[i] = codeP; }

    // 24 MFMAs: per stripe q, A=h1g1 (4-chain), B=h1g2'+h2'g1 (8-chain).
    __builtin_amdgcn_s_setprio(1);
    f16v A0 = Z, B0v = Z, A1 = Z, B1v = Z;
#pragma unroll
    for (int kc = 0; kc < 4; ++kc) {
      A0  = __builtin_amdgcn_mfma_f32_32x32x16_f16(afr[0][0][kc], b0[kc], A0,  0, 0, 0);
      A1  = __builtin_amdgcn_mfma_f32_32x32x16_f16(afr[1][0][kc], b0[kc], A1,  0, 0, 0);
      B0v = __builtin_amdgcn_mfma_f32_32x32x16_f16(afr[0][0][kc], b1[kc], B0v, 0, 0, 0);
      B1v = __builtin_amdgcn_mfma_f32_32x32x16_f16(afr[1][0][kc], b1[kc], B1v, 0, 0, 0);
    }
#pragma unroll
    for (int kc = 0; kc < 4; ++kc) {
      B0v = __builtin_amdgcn_mfma_f32_32x32x16_f16(afr[0][1][kc], b0[kc], B0v, 0, 0, 0);
      B1v = __builtin_amdgcn_mfma_f32_32x32x16_f16(afr[1][1][kc], b0[kc], B1v, 0, 0, 0);
    }
    __builtin_amdgcn_s_setprio(0);

    // dist(t) into regs (cs consumed here -> its lgkm wait stays in-body,
    // closing the reuse window before next body's DMA over this region).
#pragma unroll
    for (int i = 0; i < 16; ++i) {
      distP[i]      = fmaf(-2.f, fmaf(B0v[i], 2.44140625e-4f, A0[i]), cs);
      distP[16 + i] = fmaf(-2.f, fmaf(B1v[i], 2.44140625e-4f, A1[i]), cs);
    }
    codeP = (unsigned)((t * 4 + w) * 32 + col);
  }
  // Final epilogue: tile NBODY-1.
#pragma unroll
  for (int i = 0; i < 32; ++i)
    if (distP[i] < bestD[i]) { bestD[i] = distP[i]; bestC[i] = codeP; }

  // ---- Reduce across the 32 col-lanes (fkey u64 min: float order incl.
  // negatives, lowest code on exact ties), then across 4 waves via LDS.
  unsigned long long key[32];
#pragma unroll
  for (int i = 0; i < 32; ++i)
    key[i] = ((unsigned long long)fkey(bestD[i]) << 32) | bestC[i];
#pragma unroll
  for (int i = 0; i < 32; ++i) {
#pragma unroll
    for (int m = 1; m < 32; m <<= 1) {
      const unsigned long long o = __shfl_xor(key[i], m, 64);
      if (o < key[i]) key[i] = o;
    }
  }
  if (col == 0) {
#pragma unroll
    for (int i = 0; i < 32; ++i) {
      const int ii = i & 15, q = i >> 4;
      const int row = q * 32 + (ii & 3) + 8 * (ii >> 2) + 4 * half;
      ldsRed[row][w] = key[i];
    }
  }
  __syncthreads();
  if (tid < BROWS) {
    unsigned long long a = ldsRed[tid][0];
    const unsigned long long b = ldsRed[tid][1];
    const unsigned long long c = ldsRed[tid][2];
    const unsigned long long d = ldsRed[tid][3];
    if (b < a) a = b;
    if (c < a) a = c;
    if (d < a) a = d;
    out[blockRow + tid] = (int)(unsigned)(a & 0xFFFFFFFFull);
  }
}

extern "C" void kernel_launch(void* const* d_in, const int* in_sizes, int n_in,
                              void* d_out, int out_size, void* d_ws, size_t ws_size,
                              hipStream_t stream) {
  const float* x  = (const float*)d_in[0];   // [N, 64] fp32
  const float* cb = (const float*)d_in[1];   // [K, 64] fp32
  int* out = (int*)d_out;                    // [N] int32

  // ws: bSwz group units (256 x 8448 B = 2.06 MB)
  _Float16* bSwz = (_Float16*)d_ws;

  vq_pre_kernel<<<dim3(KC * 4 / PTPB), dim3(PTPB), 0, stream>>>(cb, bSwz);
  vq_mfma_kernel<<<dim3(NROWS / BROWS), dim3(TPB), 0, stream>>>(x, bSwz, out);
}